// Round 1
// baseline (825.660 us; speedup 1.0000x reference)
//
#include <hip/hip_runtime.h>
#include <math.h>

#define B_   32
#define T_   64
#define D_   300
#define H_   256
#define G4H  1024   // 4*H
#define M_   64
#define C_   5

__device__ __forceinline__ float sigmoidf_(float x) { return 1.0f / (1.0f + expf(-x)); }

// ---------------------------------------------------------------------------
// K1: length[b] = number of t with max_d |x[b,t,d]| > 0
// ---------------------------------------------------------------------------
__global__ void k_length(const float* __restrict__ x, int* __restrict__ length) {
    const int b = blockIdx.x;
    const int t = threadIdx.x;  // 64 threads = 1 wave
    float mv = 0.f;
    const float* row = x + (size_t)(b * T_ + t) * D_;
    for (int d = 0; d < D_; ++d) mv = fmaxf(mv, fabsf(row[d]));
    unsigned long long m = __ballot(mv > 0.f);
    if (t == 0) length[b] = __popcll(m);
}

// ---------------------------------------------------------------------------
// K2: xw[dir][row][col] = bias[col] + sum_k x[row][k] * W[k][col]
//     row = b*T + t (2048 rows), col in [0,1024), k in [0,300)
//     Simple LDS-tiled fp32 GEMM, 64x64 tile, 4x4 per thread.
// ---------------------------------------------------------------------------
__global__ void k_xw(const float* __restrict__ x,
                     const float* __restrict__ Wfw, const float* __restrict__ bfw,
                     const float* __restrict__ Wbw, const float* __restrict__ bbw,
                     float* __restrict__ xw) {
    const int colTile = blockIdx.x;   // 0..15
    const int rowTile = blockIdx.y;   // 0..31
    const int dir     = blockIdx.z;   // 0..1
    const float* W    = dir ? Wbw : Wfw;
    const float* bias = dir ? bbw : bfw;

    __shared__ float As[64][33];  // +1 pad: avoid same-bank across tr
    __shared__ float Bs[32][64];

    const int tid = threadIdx.x;       // 256
    const int tr  = tid >> 4;          // 0..15
    const int tc  = tid & 15;          // 0..15
    const int row0 = rowTile * 64, col0 = colTile * 64;

    float acc[4][4] = {};

    for (int k0 = 0; k0 < 320; k0 += 32) {
        #pragma unroll
        for (int i = 0; i < 8; ++i) {
            int e = tid + i * 256;
            int r = e >> 5, kk = e & 31;
            int k = k0 + kk;
            As[r][kk] = (k < D_) ? x[(size_t)(row0 + r) * D_ + k] : 0.f;
        }
        #pragma unroll
        for (int i = 0; i < 8; ++i) {
            int e = tid + i * 256;
            int kk = e >> 6, cc = e & 63;
            int k = k0 + kk;
            Bs[kk][cc] = (k < D_) ? W[(size_t)k * G4H + col0 + cc] : 0.f;
        }
        __syncthreads();
        #pragma unroll
        for (int kk = 0; kk < 32; ++kk) {
            float a0 = As[tr * 4 + 0][kk], a1 = As[tr * 4 + 1][kk];
            float a2 = As[tr * 4 + 2][kk], a3 = As[tr * 4 + 3][kk];
            float b0 = Bs[kk][tc * 4 + 0], b1 = Bs[kk][tc * 4 + 1];
            float b2 = Bs[kk][tc * 4 + 2], b3 = Bs[kk][tc * 4 + 3];
            acc[0][0] += a0 * b0; acc[0][1] += a0 * b1; acc[0][2] += a0 * b2; acc[0][3] += a0 * b3;
            acc[1][0] += a1 * b0; acc[1][1] += a1 * b1; acc[1][2] += a1 * b2; acc[1][3] += a1 * b3;
            acc[2][0] += a2 * b0; acc[2][1] += a2 * b1; acc[2][2] += a2 * b2; acc[2][3] += a2 * b3;
            acc[3][0] += a3 * b0; acc[3][1] += a3 * b1; acc[3][2] += a3 * b2; acc[3][3] += a3 * b3;
        }
        __syncthreads();
    }

    #pragma unroll
    for (int i = 0; i < 4; ++i) {
        #pragma unroll
        for (int j = 0; j < 4; ++j) {
            int col = col0 + tc * 4 + j;
            xw[(size_t)dir * 2048 * G4H + (size_t)(row0 + tr * 4 + i) * G4H + col] =
                acc[i][j] + bias[col];
        }
    }
}

// ---------------------------------------------------------------------------
// K3: the LSTM recurrence. One block per (dir, b); 256 threads (one per hidden
// column j). h double-buffered in LDS; c in a register. W_h rows streamed
// from global (L2-resident).
// ---------------------------------------------------------------------------
__global__ void k_lstm(const float* __restrict__ Wfw, const float* __restrict__ Wbw,
                       const float* __restrict__ xw, const int* __restrict__ length,
                       float* __restrict__ lout) {
    const int dir = blockIdx.x >> 5;
    const int b   = blockIdx.x & 31;
    const int j   = threadIdx.x;  // 0..255

    const float* Wh = (dir ? Wbw : Wfw) + (size_t)D_ * G4H;  // rows 300..555

    __shared__ float hbuf[2][H_];
    hbuf[0][j] = 0.f;
    float c = 0.f;
    const int len = length[b];
    __syncthreads();

    for (int s = 0; s < T_; ++s) {
        const int t = dir ? (T_ - 1 - s) : s;
        const float* xr = xw + ((size_t)(dir * B_ + b) * T_ + t) * G4H;
        float z0 = xr[j], z1 = xr[H_ + j], z2 = xr[2 * H_ + j], z3 = xr[3 * H_ + j];

        const int cur = s & 1;
        const float* wp = Wh + j;
        #pragma unroll 8
        for (int k = 0; k < H_; ++k) {
            float hk = hbuf[cur][k];
            z0 += hk * wp[0];
            z1 += hk * wp[H_];
            z2 += hk * wp[2 * H_];
            z3 += hk * wp[3 * H_];
            wp += G4H;
        }

        float ig = sigmoidf_(z0);
        float jg = tanhf(z1);
        float fg = sigmoidf_(z2 + 1.0f);
        float og = sigmoidf_(z3);
        float cn = fg * c + ig * jg;
        float hn = og * tanhf(cn);

        bool  msk   = (t < len);
        float hout  = msk ? hn : 0.f;
        float hkeep = msk ? hn : hbuf[cur][j];
        if (msk) c = cn;

        lout[(size_t)(b * T_ + t) * (2 * H_) + dir * H_ + j] = hout;
        hbuf[cur ^ 1][j] = hkeep;
        __syncthreads();
    }
}

// ---------------------------------------------------------------------------
// K4: einsum partials. partials[m][chunk][d] = sum_{b in chunk, t} ent[m,b,t,d]*lout[b,t,d]
// ---------------------------------------------------------------------------
__global__ void k_einsum(const float* __restrict__ ent, const float* __restrict__ lout,
                         float* __restrict__ partials) {
    const int chunk = blockIdx.x;  // 0..7 (4 b's each)
    const int m     = blockIdx.y;  // 0..63
    const int d     = threadIdx.x; // 0..511
    float acc = 0.f;
    for (int b = chunk * 4; b < chunk * 4 + 4; ++b) {
        const float* ep = ent + ((size_t)(m * B_ + b) * T_) * (2 * H_) + d;
        const float* lp = lout + ((size_t)b * T_) * (2 * H_) + d;
        #pragma unroll 4
        for (int t = 0; t < T_; ++t) {
            acc += ep[(size_t)t * 512] * lp[(size_t)t * 512];
        }
    }
    partials[(size_t)(m * 8 + chunk) * 512 + d] = acc;
}

// ---------------------------------------------------------------------------
// K5: reduce partials -> output_f[m][:] (divided by T), then l1 = relu(of @ W1 + b1)
// one block per m, 256 threads (one per l1 column)
// ---------------------------------------------------------------------------
__global__ void k_l1(const float* __restrict__ partials, const float* __restrict__ W1,
                     const float* __restrict__ b1, float* __restrict__ l1) {
    const int m = blockIdx.x;
    const int j = threadIdx.x;  // 0..255
    __shared__ float of[512];
    for (int d = j; d < 512; d += 256) {
        float s = 0.f;
        #pragma unroll
        for (int cc = 0; cc < 8; ++cc) s += partials[(size_t)(m * 8 + cc) * 512 + d];
        of[d] = s * (1.0f / T_);
    }
    __syncthreads();
    float z = b1[j];
    for (int k = 0; k < 512; ++k) z += of[k] * W1[(size_t)k * H_ + j];
    l1[(size_t)m * H_ + j] = fmaxf(z, 0.f);
}

// ---------------------------------------------------------------------------
// K6: pred = sigmoid(l1 @ W2 + b2) -> out[0:320]; loss -> out[320]
// ---------------------------------------------------------------------------
__global__ void k_head(const float* __restrict__ l1, const float* __restrict__ W2,
                       const float* __restrict__ b2, const int* __restrict__ labels,
                       float* __restrict__ out) {
    const int tid = threadIdx.x;  // 320 threads
    __shared__ float red[320];
    float term = 0.f;
    if (tid < 320) {
        int m = tid / 5, cc = tid % 5;
        float z = b2[cc];
        for (int k = 0; k < H_; ++k) z += l1[(size_t)m * H_ + k] * W2[(size_t)k * C_ + cc];
        float p = 1.f / (1.f + expf(-z));
        out[tid] = p;
        term = -(float)labels[tid] * logf(p);
    }
    red[tid] = term;
    __syncthreads();
    if (tid == 0) {
        float s = 0.f;
        for (int i = 0; i < 320; ++i) s += red[i];
        out[320] = s / (float)C_;
    }
}

// ---------------------------------------------------------------------------
extern "C" void kernel_launch(void* const* d_in, const int* in_sizes, int n_in,
                              void* d_out, int out_size, void* d_ws, size_t ws_size,
                              hipStream_t stream) {
    const float* x      = (const float*)d_in[0];
    const float* ent    = (const float*)d_in[1];
    const int*   labels = (const int*)d_in[2];
    const float* Wfw    = (const float*)d_in[3];
    const float* bfw    = (const float*)d_in[4];
    const float* Wbw    = (const float*)d_in[5];
    const float* bbw    = (const float*)d_in[6];
    const float* W1     = (const float*)d_in[7];
    const float* b1     = (const float*)d_in[8];
    const float* W2     = (const float*)d_in[9];
    const float* b2     = (const float*)d_in[10];
    float* out = (float*)d_out;

    float* ws       = (float*)d_ws;
    float* xw       = ws;                          // 2*2048*1024 = 4,194,304
    float* lout     = xw + 2 * 2048 * 1024;        // 32*64*512   = 1,048,576
    float* partials = lout + 32 * 64 * 512;        // 64*8*512    =   262,144
    float* l1       = partials + 64 * 8 * 512;     // 64*256      =    16,384
    int*   length   = (int*)(l1 + 64 * 256);       // 32 ints

    k_length<<<32, 64, 0, stream>>>(x, length);
    k_xw<<<dim3(16, 32, 2), 256, 0, stream>>>(x, Wfw, bfw, Wbw, bbw, xw);
    k_lstm<<<64, 256, 0, stream>>>(Wfw, Wbw, xw, length, lout);
    k_einsum<<<dim3(8, 64), 512, 0, stream>>>(ent, lout, partials);
    k_l1<<<64, 256, 0, stream>>>(partials, W1, b1, l1);
    k_head<<<1, 320, 0, stream>>>(l1, W2, b2, labels, out);
}